// Round 11
// baseline (284.107 us; speedup 1.0000x reference)
//
#include <hip/hip_runtime.h>
#include <hip/hip_bf16.h>

#define NN 50000
#define EE 800000
#define FF 128
#define HH 128
#define HID2 64
#define TT 8
#define GG 64
#define NB 196          // buckets of 256 dst nodes (NN < 196*256; NN < 2^16)
#define NSB 256         // build blocks
#define EPB (EE / NSB)  // 3125 edges per block
#define NPAD 50048      // NN padded to 64 (782 * 64)

using frag_ab = __attribute__((ext_vector_type(8))) short;  // 8 bf16
using frag_cd = __attribute__((ext_vector_type(4))) float;  // 4 fp32

__device__ inline unsigned short f2bf(float f) {
    union { float f; unsigned u; } v; v.f = f;
    unsigned r = v.u + 0x7fff + ((v.u >> 16) & 1);  // RNE
    return (unsigned short)(r >> 16);
}

// ---- grid barrier: 256 co-resident blocks (capacity >> grid), distinct slot
__device__ inline void gbar(int* __restrict__ bar, int idx) {
    __syncthreads();
    if (threadIdx.x == 0) {
        __threadfence();
        atomicAdd(&bar[idx], 1);
        while (__hip_atomic_load(&bar[idx], __ATOMIC_RELAXED,
                                 __HIP_MEMORY_SCOPE_AGENT) < NSB) {
            __builtin_amdgcn_s_sleep(1);
        }
        __threadfence();
    }
    __syncthreads();
}

// ---- K_BUILD: hist+Wt+gsum0 | colscan | bbase | scatter | CSR  (1 launch) --
__global__ __launch_bounds__(256) void k_build(const int* __restrict__ src,
                                               const int* __restrict__ dst,
                                               const float* __restrict__ W,
                                               int* __restrict__ table,
                                               int* __restrict__ ctot,
                                               int* __restrict__ bbase,
                                               unsigned* __restrict__ etmp,
                                               int* __restrict__ row_ptr,
                                               float* __restrict__ dinv,
                                               int* __restrict__ srcs,
                                               unsigned short* __restrict__ wt_bf,
                                               float* __restrict__ gsum,
                                               int* __restrict__ bar) {
    __shared__ int shm[512];
    int t = threadIdx.x, blk = blockIdx.x;

    // ---- phase A: per-(block,bucket) histogram + side jobs ----
    if (blk < 64) {                       // W[k][c] -> wt_bf[c][k]
        int gid = blk * 256 + t;
        int c = gid >> 7, k = gid & 127;
        wt_bf[gid] = f2bf(W[k * 128 + c]);
    } else if (blk < 96) {                // zero gsum
        int gid = (blk - 64) * 256 + t;
        gsum[gid] = 0.f;
    }
    for (int i = t; i < NB; i += 256) shm[i] = 0;
    __syncthreads();
    {
        int e0 = blk * EPB;
        for (int e = e0 + t; e < e0 + EPB; e += 256)
            atomicAdd(&shm[dst[e] >> 8], 1);
    }
    __syncthreads();
    for (int i = t; i < NB; i += 256) table[blk * NB + i] = shm[i];
    gbar(bar, 0);

    // ---- phase B: column scan (blocks 0..195) ----
    if (blk < NB) {
        int b = blk;
        int v = table[t * NB + b];
        shm[t] = v;
        __syncthreads();
        for (int off = 1; off < 256; off <<= 1) {
            int a = shm[t];
            int w = (t >= off) ? shm[t - off] : 0;
            __syncthreads();
            shm[t] = a + w;
            __syncthreads();
        }
        table[t * NB + b] = shm[t] - v;
        if (t == 255) ctot[b] = shm[255];
    }
    gbar(bar, 1);

    // ---- phase C: scan of 196 column totals -> bbase (block 0) ----
    if (blk == 0) {
        int v = (t < NB) ? ctot[t] : 0;
        shm[t] = v;
        __syncthreads();
        for (int off = 1; off < 256; off <<= 1) {
            int a = shm[t];
            int w = (t >= off) ? shm[t - off] : 0;
            __syncthreads();
            shm[t] = a + w;
            __syncthreads();
        }
        if (t < NB) bbase[t] = shm[t] - v;
        if (t == 0) bbase[NB] = EE;
    }
    gbar(bar, 2);

    // ---- phase D: scatter edges into bucket order ----
    {
        int* ofs = shm;          // [NB]
        int* cur = shm + 256;    // [NB]
        for (int i = t; i < NB; i += 256) {
            ofs[i] = table[blk * NB + i] + bbase[i];
            cur[i] = 0;
        }
        __syncthreads();
        int e0 = blk * EPB;
        for (int e = e0 + t; e < e0 + EPB; e += 256) {
            int d = dst[e];
            int b = d >> 8;
            int r = atomicAdd(&cur[b], 1);
            etmp[ofs[b] + r] = ((unsigned)d << 16) | (unsigned)src[e];
        }
    }
    gbar(bar, 3);

    // ---- phase E: per-bucket hist -> scan -> row_ptr/dinv -> CSR fill ----
    if (blk < NB) {
        int b = blk;
        int* s = shm;
        int* cur = shm + 256;
        s[t] = 0;
        __syncthreads();
        int e0 = bbase[b], e1 = bbase[b + 1];
        for (int e = e0 + t; e < e1; e += 256)
            atomicAdd(&s[(etmp[e] >> 16) & 255], 1);
        __syncthreads();
        int v = s[t];
        for (int off = 1; off < 256; off <<= 1) {
            int a = s[t];
            int w = (t >= off) ? s[t - off] : 0;
            __syncthreads();
            s[t] = a + w;
            __syncthreads();
        }
        int excl = s[t] - v + e0;   // e0 == row_ptr[b*256]
        int node = b * 256 + t;
        if (node < NN) {
            row_ptr[node] = excl;
            dinv[node] = rsqrtf((float)(v + 1));  // +1 self-loop
        }
        if (b == NB - 1 && t == 0) row_ptr[NN] = EE;
        cur[t] = excl;
        __syncthreads();
        for (int e = e0 + t; e < e1; e += 256) {
            unsigned u = etmp[e];
            int slot = atomicAdd(&cur[(u >> 16) & 255], 1);
            srcs[slot] = (int)(u & 0xffffu);
        }
    }
}

// ---- K4: MFMA GEMM  hs = bf16( (x @ W) * dinv[row] ), direct fp32 x -------
__global__ __launch_bounds__(256) void k_gemm(const float* __restrict__ x,
                                              const unsigned short* __restrict__ wt_bf,
                                              const float* __restrict__ dinv,
                                              unsigned short* __restrict__ hs) {
    int tid = threadIdx.x;
    int w = tid >> 6, lane = tid & 63;
    int m = lane & 15, quad = lane >> 4;
    int r0 = blockIdx.x * 64 + w * 16;        // 782 blocks * 64 = NPAD exactly
    int row = r0 + m;
    frag_cd acc[8];
#pragma unroll
    for (int nt = 0; nt < 8; nt++) acc[nt] = frag_cd{0.f, 0.f, 0.f, 0.f};

#pragma unroll
    for (int k0 = 0; k0 < 128; k0 += 32) {
        unsigned short av[8];
        if (row < NN) {
            const float4* p = (const float4*)(x + (size_t)row * 128 + k0 + quad * 8);
            float4 a0 = p[0], a1 = p[1];
            av[0] = f2bf(a0.x); av[1] = f2bf(a0.y); av[2] = f2bf(a0.z); av[3] = f2bf(a0.w);
            av[4] = f2bf(a1.x); av[5] = f2bf(a1.y); av[6] = f2bf(a1.z); av[7] = f2bf(a1.w);
        } else {
#pragma unroll
            for (int j = 0; j < 8; j++) av[j] = 0;
        }
        frag_ab a = *(const frag_ab*)av;
#pragma unroll
        for (int nt = 0; nt < 8; nt++) {
            frag_ab bfr = *(const frag_ab*)(wt_bf + (size_t)(nt * 16 + m) * 128 + k0 + quad * 8);
            acc[nt] = __builtin_amdgcn_mfma_f32_16x16x32_bf16(a, bfr, acc[nt], 0, 0, 0);
        }
    }
#pragma unroll
    for (int reg = 0; reg < 4; reg++) {
        int gr = r0 + quad * 4 + reg;
        if (gr < NN) {
            float di = dinv[gr];
#pragma unroll
            for (int nt = 0; nt < 8; nt++)
                hs[(size_t)gr * 128 + nt * 16 + m] = f2bf(acc[nt][reg] * di);
        }
    }
}

// ---------------- K5: gather + bias + relu + fused hierarchical pool -------
// 16 quarter-waves/block; qwave = ONE node's 256B row (16 lanes x uint4).
// 16 nodes/block, 3125 blocks (grid exact). 4-deep pipeline, VGPR ~36.
#define ACC8(u) \
    a0 += __uint_as_float((u).x << 16); a1 += __uint_as_float((u).x & 0xffff0000u); \
    a2 += __uint_as_float((u).y << 16); a3 += __uint_as_float((u).y & 0xffff0000u); \
    a4 += __uint_as_float((u).z << 16); a5 += __uint_as_float((u).z & 0xffff0000u); \
    a6 += __uint_as_float((u).w << 16); a7 += __uint_as_float((u).w & 0xffff0000u);

__global__ __launch_bounds__(256) void k_aggr(const uint4* __restrict__ hs4,
                                              const int* __restrict__ row_ptr,
                                              const int* __restrict__ srcs,
                                              const float* __restrict__ dinv,
                                              const float* __restrict__ bias,
                                              const int* __restrict__ batch,
                                              float* __restrict__ gsum) {
    __shared__ float gacc[8 * 128];   // 4 KB: 8 group slots (span>8 -> global)
    int tid = threadIdx.x;
    int qid = tid >> 4, sub = tid & 15;
    int i_base = blockIdx.x * 16;
    int i = i_base + qid;             // grid exact: i < NN always
    int g_first = batch[i_base];
    int last = i_base + 15; if (last >= NN) last = NN - 1;
    int gspan = batch[last] - g_first + 1;
    bool lds_pool = (gspan <= 8);
    int slots = lds_pool ? gspan : 0;
    for (int idx = tid; idx < slots * 128; idx += 256) gacc[idx] = 0.f;
    __syncthreads();

    const float4* b4 = (const float4*)(bias + sub * 8);
    float4 bb0 = b4[0], bb1 = b4[1];

    float di = dinv[i];
    uint4 su = hs4[(size_t)i * 16 + sub];
    float a0 = __uint_as_float(su.x << 16);
    float a1 = __uint_as_float(su.x & 0xffff0000u);
    float a2 = __uint_as_float(su.y << 16);
    float a3 = __uint_as_float(su.y & 0xffff0000u);
    float a4 = __uint_as_float(su.z << 16);
    float a5 = __uint_as_float(su.z & 0xffff0000u);
    float a6 = __uint_as_float(su.w << 16);
    float a7 = __uint_as_float(su.w & 0xffff0000u);
    int e = row_ptr[i], e1 = row_ptr[i + 1];
    for (; e + 3 < e1; e += 4) {
        int s0 = srcs[e], s1 = srcs[e + 1], s2 = srcs[e + 2], s3 = srcs[e + 3];
        uint4 u0 = hs4[(size_t)s0 * 16 + sub];
        uint4 u1 = hs4[(size_t)s1 * 16 + sub];
        uint4 u2 = hs4[(size_t)s2 * 16 + sub];
        uint4 u3 = hs4[(size_t)s3 * 16 + sub];
        ACC8(u0) ACC8(u1) ACC8(u2) ACC8(u3)
    }
    for (; e < e1; ++e) {
        uint4 u0 = hs4[(size_t)srcs[e] * 16 + sub];
        ACC8(u0)
    }
    float r0 = fmaxf(fmaf(a0, di, bb0.x), 0.f);
    float r1 = fmaxf(fmaf(a1, di, bb0.y), 0.f);
    float r2 = fmaxf(fmaf(a2, di, bb0.z), 0.f);
    float r3 = fmaxf(fmaf(a3, di, bb0.w), 0.f);
    float r4 = fmaxf(fmaf(a4, di, bb1.x), 0.f);
    float r5 = fmaxf(fmaf(a5, di, bb1.y), 0.f);
    float r6 = fmaxf(fmaf(a6, di, bb1.z), 0.f);
    float r7 = fmaxf(fmaf(a7, di, bb1.w), 0.f);
    int lg = batch[i] - g_first;
    float* gp = lds_pool ? &gacc[lg * 128 + sub * 8]
                         : &gsum[(g_first + lg) * 128 + sub * 8];
    atomicAdd(&gp[0], r0); atomicAdd(&gp[1], r1);
    atomicAdd(&gp[2], r2); atomicAdd(&gp[3], r3);
    atomicAdd(&gp[4], r4); atomicAdd(&gp[5], r5);
    atomicAdd(&gp[6], r6); atomicAdd(&gp[7], r7);
    __syncthreads();
    for (int idx = tid; idx < slots * 128; idx += 256) {
        float v = gacc[idx];
        if (v != 0.f)
            atomicAdd(&gsum[(g_first + (idx >> 7)) * 128 + (idx & 127)], v);
    }
}

__device__ inline int lbound(const int* __restrict__ a, int n, int key) {
    int lo = 0, hi = n;
    while (lo < hi) {
        int mid = (lo + hi) >> 1;
        if (a[mid] < key) lo = mid + 1;
        else hi = mid;
    }
    return lo;
}

// ---------------- K7: head (mean, fc1 + relu, actor softmax, critic) -------
__global__ __launch_bounds__(64) void k_head(const float* __restrict__ gsum,
                                             const int* __restrict__ batch,
                                             const float* __restrict__ fc1_w,
                                             const float* __restrict__ fc1_b,
                                             const float* __restrict__ actor_w,
                                             const float* __restrict__ actor_b,
                                             const float* __restrict__ critic_w,
                                             const float* __restrict__ critic_b,
                                             float* __restrict__ out) {
    __shared__ float gs[128];
    __shared__ float zs[64];
    __shared__ float ls[8], es[8];
    int g = blockIdx.x, t = threadIdx.x;
    int lo = lbound(batch, NN, g), hi = lbound(batch, NN, g + 1);
    float invc = 1.f / fmaxf((float)(hi - lo), 1.f);
    gs[t] = gsum[g * 128 + t] * invc;
    gs[t + 64] = gsum[g * 128 + 64 + t] * invc;
    __syncthreads();
    float z = fc1_b[t];
    for (int k = 0; k < 128; k++) z = fmaf(gs[k], fc1_w[k * 64 + t], z);
    zs[t] = fmaxf(z, 0.f);
    __syncthreads();
    if (t < 8) {
        float l = actor_b[t];
        for (int k = 0; k < 64; k++) l = fmaf(zs[k], actor_w[k * 8 + t], l);
        ls[t] = l;
    }
    __syncthreads();
    if (t < 8) {
        float m = ls[0];
#pragma unroll
        for (int j = 1; j < 8; j++) m = fmaxf(m, ls[j]);
        es[t] = expf(ls[t] - m);
    }
    __syncthreads();
    if (t < 8) {
        float ssum = 0.f;
#pragma unroll
        for (int j = 0; j < 8; j++) ssum += es[j];
        out[g * 8 + t] = es[t] / ssum;
    }
    if (t == 32) {
        float v = critic_b[0];
        for (int k = 0; k < 64; k++) v = fmaf(zs[k], critic_w[k], v);
        out[GG * TT + g] = v;
    }
}

extern "C" void kernel_launch(void* const* d_in, const int* in_sizes, int n_in,
                              void* d_out, int out_size, void* d_ws, size_t ws_size,
                              hipStream_t stream) {
    const float* x        = (const float*)d_in[0];
    const int*   ei       = (const int*)d_in[1];
    const int*   batch    = (const int*)d_in[2];
    const float* W        = (const float*)d_in[3];
    const float* b        = (const float*)d_in[4];
    const float* fc1_w    = (const float*)d_in[5];
    const float* fc1_b    = (const float*)d_in[6];
    const float* actor_w  = (const float*)d_in[7];
    const float* actor_b  = (const float*)d_in[8];
    const float* critic_w = (const float*)d_in[9];
    const float* critic_b = (const float*)d_in[10];
    float* out = (float*)d_out;

    char* ws = (char*)d_ws;
    size_t off = 0;
    unsigned short* hs    = (unsigned short*)(ws + off); off += (size_t)NN * 128 * 2 + 64;  // 12.8 MB
    unsigned short* wt_bf = (unsigned short*)(ws + off); off += (size_t)128 * 128 * 2;      // 32 KB
    float* dinv      = (float*)(ws + off);    off += (size_t)NN * 4;
    int*   row_ptr   = (int*)(ws + off);      off += (size_t)(NN + 1) * 4 + 12;
    int*   srcs      = (int*)(ws + off);      off += (size_t)EE * 4;       // 3.2 MB
    unsigned* etmp   = (unsigned*)(ws + off); off += (size_t)EE * 4;       // 3.2 MB
    int*   table     = (int*)(ws + off);      off += (size_t)NSB * NB * 4; // 200 KB
    int*   bbase     = (int*)(ws + off);      off += (size_t)(NB + 1) * 4 + 12;
    int*   ctot      = (int*)(ws + off);      off += (size_t)NB * 4 + 16;
    float* gsum      = (float*)(ws + off);    off += (size_t)GG * HH * 4;
    int*   bar       = (int*)(ws + off);      off += 64;

    const int* src = ei;        // edge_index[0]
    const int* dst = ei + EE;   // edge_index[1]

    hipMemsetAsync(bar, 0, 64, stream);
    k_build<<<NSB, 256, 0, stream>>>(src, dst, W, table, ctot, bbase, etmp,
                                     row_ptr, dinv, srcs, wt_bf, gsum, bar);
    k_gemm<<<NPAD / 64, 256, 0, stream>>>(x, wt_bf, dinv, hs);
    k_aggr<<<NN / 16, 256, 0, stream>>>((const uint4*)hs, row_ptr, srcs,
                                        dinv, b, batch, gsum);
    k_head<<<GG, 64, 0, stream>>>(gsum, batch, fc1_w, fc1_b, actor_w, actor_b,
                                  critic_w, critic_b, out);
}

// Round 12
// 232.985 us; speedup vs baseline: 1.2194x; 1.2194x over previous
//
#include <hip/hip_runtime.h>
#include <hip/hip_bf16.h>

#define NN 50000
#define EE 800000
#define FF 128
#define HH 128
#define HID2 64
#define TT 8
#define GG 64
#define NB 196          // buckets of 256 dst nodes (NN < 196*256; NN < 2^16)
#define NSB 256         // scatter blocks
#define EPB (EE / NSB)  // 3125 edges per scatter block
#define NPAD 50048      // NN padded to 64 (782 * 64)
#define SLABU ((size_t)NN * 32)   // ushorts per feature-quarter slab (3.2 MB)

using frag_ab = __attribute__((ext_vector_type(8))) short;  // 8 bf16
using frag_cd = __attribute__((ext_vector_type(4))) float;  // 4 fp32

__device__ inline unsigned short f2bf(float f) {
    union { float f; unsigned u; } v; v.f = f;
    unsigned r = v.u + 0x7fff + ((v.u >> 16) & 1);  // RNE
    return (unsigned short)(r >> 16);
}

// ---- K_FRONT: kb1 LDS histogram  +  W->Wt bf16  +  gsum zero  (1 launch) --
__global__ __launch_bounds__(256) void k_front(const int* __restrict__ dst,
                                               const float* __restrict__ W,
                                               int* __restrict__ table,
                                               unsigned short* __restrict__ wt_bf,
                                               float* __restrict__ gsum) {
    __shared__ int cnt[NB];
    int t = threadIdx.x, blk = blockIdx.x;
    if (blk < 64) {                       // W[k][c] -> wt_bf[c][k]
        int gid = blk * 256 + t;
        int c = gid >> 7, k = gid & 127;
        wt_bf[gid] = f2bf(W[k * 128 + c]);
    }
    if (blk >= 64 && blk < 96) {          // zero gsum
        int gid = (blk - 64) * 256 + t;
        gsum[gid] = 0.f;
    }
    for (int i = t; i < NB; i += 256) cnt[i] = 0;
    __syncthreads();
    int e0 = blk * EPB;
    for (int e = e0 + t; e < e0 + EPB; e += 256)
        atomicAdd(&cnt[dst[e] >> 8], 1);
    __syncthreads();
    for (int i = t; i < NB; i += 256) table[blk * NB + i] = cnt[i];
}

// ---- KB2a: per-bucket column scan of table (196 blocks) -------------------
__global__ __launch_bounds__(256) void kb2a(int* __restrict__ table,
                                            int* __restrict__ ctot) {
    __shared__ int s[256];
    int t = threadIdx.x, b = blockIdx.x;
    int v = table[t * NB + b];
    s[t] = v;
    __syncthreads();
    for (int off = 1; off < 256; off <<= 1) {
        int a = s[t];
        int w = (t >= off) ? s[t - off] : 0;
        __syncthreads();
        s[t] = a + w;
        __syncthreads();
    }
    table[t * NB + b] = s[t] - v;          // exclusive within column
    if (t == 255) ctot[b] = s[255];
}

// ---- KB2b: exclusive scan of 196 column totals -> bbase -------------------
__global__ __launch_bounds__(256) void kb2b(const int* __restrict__ ctot,
                                            int* __restrict__ bbase) {
    __shared__ int s[256];
    int b = threadIdx.x;
    int v = (b < NB) ? ctot[b] : 0;
    s[b] = v;
    __syncthreads();
    for (int off = 1; off < 256; off <<= 1) {
        int a = s[b];
        int w = (b >= off) ? s[b - off] : 0;
        __syncthreads();
        s[b] = a + w;
        __syncthreads();
    }
    if (b < NB) bbase[b] = s[b] - v;
    if (b == 0) bbase[NB] = EE;
}

// ---- KB3: scatter edges into bucket order (packed dst<<16|src) ------------
__global__ __launch_bounds__(256) void kb3(const int* __restrict__ src,
                                           const int* __restrict__ dst,
                                           const int* __restrict__ table,
                                           const int* __restrict__ bbase,
                                           unsigned* __restrict__ etmp) {
    __shared__ int ofs[NB];
    __shared__ int cur[NB];
    int t = threadIdx.x, blk = blockIdx.x;
    for (int i = t; i < NB; i += 256) {
        ofs[i] = table[blk * NB + i] + bbase[i];
        cur[i] = 0;
    }
    __syncthreads();
    int e0 = blk * EPB;
    for (int e = e0 + t; e < e0 + EPB; e += 256) {
        int d = dst[e];
        int b = d >> 8;
        int r = atomicAdd(&cur[b], 1);
        etmp[ofs[b] + r] = ((unsigned)d << 16) | (unsigned)src[e];
    }
}

// ---- K_CSR: per-bucket  hist -> scan -> row_ptr/dinv -> CSR fill ----------
__global__ __launch_bounds__(256) void k_csr(const unsigned* __restrict__ etmp,
                                             const int* __restrict__ bbase,
                                             int* __restrict__ row_ptr,
                                             float* __restrict__ dinv,
                                             int* __restrict__ srcs) {
    __shared__ int s[256];
    __shared__ int cur[256];
    int t = threadIdx.x, b = blockIdx.x;
    s[t] = 0;
    __syncthreads();
    int e0 = bbase[b], e1 = bbase[b + 1];
    for (int e = e0 + t; e < e1; e += 256)
        atomicAdd(&s[(etmp[e] >> 16) & 255], 1);
    __syncthreads();
    int v = s[t];
    for (int off = 1; off < 256; off <<= 1) {
        int a = s[t];
        int w = (t >= off) ? s[t - off] : 0;
        __syncthreads();
        s[t] = a + w;
        __syncthreads();
    }
    int excl = s[t] - v + e0;   // e0 == bbase[b] == row_ptr[b*256]
    int node = b * 256 + t;
    if (node < NN) {
        row_ptr[node] = excl;
        dinv[node] = rsqrtf((float)(v + 1));  // +1 self-loop
    }
    if (b == NB - 1 && t == 0) row_ptr[NN] = EE;
    cur[t] = excl;
    __syncthreads();
    for (int e = e0 + t; e < e1; e += 256) {
        unsigned u = etmp[e];
        int slot = atomicAdd(&cur[(u >> 16) & 255], 1);
        srcs[slot] = (int)(u & 0xffffu);
    }
}

// ---- K4: MFMA GEMM  hsq = bf16( (x @ W) * dinv[row] ), slab layout --------
// Slab q holds feature cols [q*32, q*32+32): hsq[q*SLABU + row*32 + (c&31)].
__global__ __launch_bounds__(256) void k_gemm(const float* __restrict__ x,
                                              const unsigned short* __restrict__ wt_bf,
                                              const float* __restrict__ dinv,
                                              unsigned short* __restrict__ hsq) {
    int tid = threadIdx.x;
    int w = tid >> 6, lane = tid & 63;
    int m = lane & 15, quad = lane >> 4;
    int r0 = blockIdx.x * 64 + w * 16;        // 782 blocks * 64 = NPAD exactly
    int row = r0 + m;
    frag_cd acc[8];
#pragma unroll
    for (int nt = 0; nt < 8; nt++) acc[nt] = frag_cd{0.f, 0.f, 0.f, 0.f};

#pragma unroll
    for (int k0 = 0; k0 < 128; k0 += 32) {
        unsigned short av[8];
        if (row < NN) {
            const float4* p = (const float4*)(x + (size_t)row * 128 + k0 + quad * 8);
            float4 a0 = p[0], a1 = p[1];
            av[0] = f2bf(a0.x); av[1] = f2bf(a0.y); av[2] = f2bf(a0.z); av[3] = f2bf(a0.w);
            av[4] = f2bf(a1.x); av[5] = f2bf(a1.y); av[6] = f2bf(a1.z); av[7] = f2bf(a1.w);
        } else {
#pragma unroll
            for (int j = 0; j < 8; j++) av[j] = 0;
        }
        frag_ab a = *(const frag_ab*)av;
#pragma unroll
        for (int nt = 0; nt < 8; nt++) {
            frag_ab bfr = *(const frag_ab*)(wt_bf + (size_t)(nt * 16 + m) * 128 + k0 + quad * 8);
            acc[nt] = __builtin_amdgcn_mfma_f32_16x16x32_bf16(a, bfr, acc[nt], 0, 0, 0);
        }
    }
#pragma unroll
    for (int reg = 0; reg < 4; reg++) {
        int gr = r0 + quad * 4 + reg;
        if (gr < NN) {
            float di = dinv[gr];
#pragma unroll
            for (int nt = 0; nt < 8; nt++) {
                int c = nt * 16 + m;
                hsq[(size_t)(c >> 5) * SLABU + (size_t)gr * 32 + (c & 31)] =
                    f2bf(acc[nt][reg] * di);
            }
        }
    }
}

// ---- K5: per-quarter gather + bias + relu + fused pool --------------------
// One dispatch per feature-quarter: working set = one 3.2 MB slab -> L2-hot.
// Block = 64 nodes; 4 lanes per node (64 B quarter-row = 4 x uint4).
#define ACC8(u) \
    a0 += __uint_as_float((u).x << 16); a1 += __uint_as_float((u).x & 0xffff0000u); \
    a2 += __uint_as_float((u).y << 16); a3 += __uint_as_float((u).y & 0xffff0000u); \
    a4 += __uint_as_float((u).z << 16); a5 += __uint_as_float((u).z & 0xffff0000u); \
    a6 += __uint_as_float((u).w << 16); a7 += __uint_as_float((u).w & 0xffff0000u);

__global__ __launch_bounds__(256) void k_aggrq(const uint4* __restrict__ slab4,
                                               const int* __restrict__ row_ptr,
                                               const int* __restrict__ srcs,
                                               const float* __restrict__ dinv,
                                               const float* __restrict__ bias_q,
                                               const int* __restrict__ batch,
                                               float* __restrict__ gsum_q) {
    __shared__ float gacc[8 * 32];   // 1 KB: 8 group slots x 32 feats
    int t = threadIdx.x;
    int grp = t >> 2, j = t & 3;
    int i_base = blockIdx.x * 64;
    int node = i_base + grp;
    int last = i_base + 63; if (last >= NN) last = NN - 1;
    int g_first = batch[i_base];
    int gspan = batch[last] - g_first + 1;
    bool lds_pool = (gspan <= 8);
    int slots = lds_pool ? gspan : 0;
    if (t < slots * 32) gacc[t] = 0.f;
    __syncthreads();

    if (node < NN) {
        const float4* b4 = (const float4*)(bias_q + j * 8);
        float4 bb0 = b4[0], bb1 = b4[1];
        float di = dinv[node];
        uint4 su = slab4[(size_t)node * 4 + j];
        float a0 = __uint_as_float(su.x << 16);
        float a1 = __uint_as_float(su.x & 0xffff0000u);
        float a2 = __uint_as_float(su.y << 16);
        float a3 = __uint_as_float(su.y & 0xffff0000u);
        float a4 = __uint_as_float(su.z << 16);
        float a5 = __uint_as_float(su.z & 0xffff0000u);
        float a6 = __uint_as_float(su.w << 16);
        float a7 = __uint_as_float(su.w & 0xffff0000u);
        int e = row_ptr[node], e1 = row_ptr[node + 1];
        for (; e + 3 < e1; e += 4) {
            int s0 = srcs[e], s1 = srcs[e + 1], s2 = srcs[e + 2], s3 = srcs[e + 3];
            uint4 u0 = slab4[(size_t)s0 * 4 + j];
            uint4 u1 = slab4[(size_t)s1 * 4 + j];
            uint4 u2 = slab4[(size_t)s2 * 4 + j];
            uint4 u3 = slab4[(size_t)s3 * 4 + j];
            ACC8(u0) ACC8(u1) ACC8(u2) ACC8(u3)
        }
        for (; e < e1; ++e) {
            uint4 u0 = slab4[(size_t)srcs[e] * 4 + j];
            ACC8(u0)
        }
        float r0 = fmaxf(fmaf(a0, di, bb0.x), 0.f);
        float r1 = fmaxf(fmaf(a1, di, bb0.y), 0.f);
        float r2 = fmaxf(fmaf(a2, di, bb0.z), 0.f);
        float r3 = fmaxf(fmaf(a3, di, bb0.w), 0.f);
        float r4 = fmaxf(fmaf(a4, di, bb1.x), 0.f);
        float r5 = fmaxf(fmaf(a5, di, bb1.y), 0.f);
        float r6 = fmaxf(fmaf(a6, di, bb1.z), 0.f);
        float r7 = fmaxf(fmaf(a7, di, bb1.w), 0.f);
        int lg = batch[node] - g_first;
        float* gp = lds_pool ? &gacc[lg * 32 + j * 8]
                             : &gsum_q[(g_first + lg) * 128 + j * 8];
        atomicAdd(&gp[0], r0); atomicAdd(&gp[1], r1);
        atomicAdd(&gp[2], r2); atomicAdd(&gp[3], r3);
        atomicAdd(&gp[4], r4); atomicAdd(&gp[5], r5);
        atomicAdd(&gp[6], r6); atomicAdd(&gp[7], r7);
    }
    __syncthreads();
    if (t < slots * 32) {
        float v = gacc[t];
        if (v != 0.f)
            atomicAdd(&gsum_q[(g_first + (t >> 5)) * 128 + (t & 31)], v);
    }
}

__device__ inline int lbound(const int* __restrict__ a, int n, int key) {
    int lo = 0, hi = n;
    while (lo < hi) {
        int mid = (lo + hi) >> 1;
        if (a[mid] < key) lo = mid + 1;
        else hi = mid;
    }
    return lo;
}

// ---------------- K7: head (mean, fc1 + relu, actor softmax, critic) -------
__global__ __launch_bounds__(64) void k_head(const float* __restrict__ gsum,
                                             const int* __restrict__ batch,
                                             const float* __restrict__ fc1_w,
                                             const float* __restrict__ fc1_b,
                                             const float* __restrict__ actor_w,
                                             const float* __restrict__ actor_b,
                                             const float* __restrict__ critic_w,
                                             const float* __restrict__ critic_b,
                                             float* __restrict__ out) {
    __shared__ float gs[128];
    __shared__ float zs[64];
    __shared__ float ls[8], es[8];
    int g = blockIdx.x, t = threadIdx.x;
    int lo = lbound(batch, NN, g), hi = lbound(batch, NN, g + 1);
    float invc = 1.f / fmaxf((float)(hi - lo), 1.f);
    gs[t] = gsum[g * 128 + t] * invc;
    gs[t + 64] = gsum[g * 128 + 64 + t] * invc;
    __syncthreads();
    float z = fc1_b[t];
    for (int k = 0; k < 128; k++) z = fmaf(gs[k], fc1_w[k * 64 + t], z);
    zs[t] = fmaxf(z, 0.f);
    __syncthreads();
    if (t < 8) {
        float l = actor_b[t];
        for (int k = 0; k < 64; k++) l = fmaf(zs[k], actor_w[k * 8 + t], l);
        ls[t] = l;
    }
    __syncthreads();
    if (t < 8) {
        float m = ls[0];
#pragma unroll
        for (int j = 1; j < 8; j++) m = fmaxf(m, ls[j]);
        es[t] = expf(ls[t] - m);
    }
    __syncthreads();
    if (t < 8) {
        float ssum = 0.f;
#pragma unroll
        for (int j = 0; j < 8; j++) ssum += es[j];
        out[g * 8 + t] = es[t] / ssum;
    }
    if (t == 32) {
        float v = critic_b[0];
        for (int k = 0; k < 64; k++) v = fmaf(zs[k], critic_w[k], v);
        out[GG * TT + g] = v;
    }
}

extern "C" void kernel_launch(void* const* d_in, const int* in_sizes, int n_in,
                              void* d_out, int out_size, void* d_ws, size_t ws_size,
                              hipStream_t stream) {
    const float* x        = (const float*)d_in[0];
    const int*   ei       = (const int*)d_in[1];
    const int*   batch    = (const int*)d_in[2];
    const float* W        = (const float*)d_in[3];
    const float* b        = (const float*)d_in[4];
    const float* fc1_w    = (const float*)d_in[5];
    const float* fc1_b    = (const float*)d_in[6];
    const float* actor_w  = (const float*)d_in[7];
    const float* actor_b  = (const float*)d_in[8];
    const float* critic_w = (const float*)d_in[9];
    const float* critic_b = (const float*)d_in[10];
    float* out = (float*)d_out;

    char* ws = (char*)d_ws;
    size_t off = 0;
    unsigned short* hsq   = (unsigned short*)(ws + off); off += (size_t)NN * 128 * 2 + 64;  // 12.8 MB
    unsigned short* wt_bf = (unsigned short*)(ws + off); off += (size_t)128 * 128 * 2;      // 32 KB
    float* dinv      = (float*)(ws + off);    off += (size_t)NN * 4;
    int*   row_ptr   = (int*)(ws + off);      off += (size_t)(NN + 1) * 4 + 12;
    int*   srcs      = (int*)(ws + off);      off += (size_t)EE * 4;       // 3.2 MB
    unsigned* etmp   = (unsigned*)(ws + off); off += (size_t)EE * 4;       // 3.2 MB
    int*   table     = (int*)(ws + off);      off += (size_t)NSB * NB * 4; // 200 KB
    int*   bbase     = (int*)(ws + off);      off += (size_t)(NB + 1) * 4 + 12;
    int*   ctot      = (int*)(ws + off);      off += (size_t)NB * 4 + 16;
    float* gsum      = (float*)(ws + off);    off += (size_t)GG * HH * 4;

    const int* src = ei;        // edge_index[0]
    const int* dst = ei + EE;   // edge_index[1]

    k_front<<<NSB, 256, 0, stream>>>(dst, W, table, wt_bf, gsum);
    kb2a<<<NB, 256, 0, stream>>>(table, ctot);
    kb2b<<<1, 256, 0, stream>>>(ctot, bbase);
    kb3<<<NSB, 256, 0, stream>>>(src, dst, table, bbase, etmp);
    k_csr<<<NB, 256, 0, stream>>>(etmp, bbase, row_ptr, dinv, srcs);
    k_gemm<<<NPAD / 64, 256, 0, stream>>>(x, wt_bf, dinv, hsq);
    for (int q = 0; q < 4; q++) {
        k_aggrq<<<NPAD / 64, 256, 0, stream>>>(
            (const uint4*)(hsq + (size_t)q * SLABU), row_ptr, srcs, dinv,
            b + q * 32, batch, gsum + q * 32);
    }
    k_head<<<GG, 64, 0, stream>>>(gsum, batch, fc1_w, fc1_b, actor_w, actor_b,
                                  critic_w, critic_b, out);
}

// Round 13
// 201.769 us; speedup vs baseline: 1.4081x; 1.1547x over previous
//
#include <hip/hip_runtime.h>
#include <hip/hip_bf16.h>

#define NN 50000
#define EE 800000
#define FF 128
#define HH 128
#define HID2 64
#define TT 8
#define GG 64
#define NB 196          // buckets of 256 dst nodes (NN < 196*256; NN < 2^16)
#define NSB 256         // scatter blocks
#define EPB (EE / NSB)  // 3125 edges per scatter block
#define NPAD 50048      // NN padded to 64 (782 * 64)

using frag_ab = __attribute__((ext_vector_type(8))) short;  // 8 bf16
using frag_cd = __attribute__((ext_vector_type(4))) float;  // 4 fp32

__device__ inline unsigned short f2bf(float f) {
    union { float f; unsigned u; } v; v.f = f;
    unsigned r = v.u + 0x7fff + ((v.u >> 16) & 1);  // RNE
    return (unsigned short)(r >> 16);
}

// ---- K_FRONT: hist (4 per-wave sub-hists) + W->Wt bf16 + gsum zero --------
__global__ __launch_bounds__(256) void k_front(const int* __restrict__ dst,
                                               const float* __restrict__ W,
                                               int* __restrict__ table,
                                               unsigned short* __restrict__ wt_bf,
                                               float* __restrict__ gsum) {
    __shared__ int cnt[4 * NB];
    int t = threadIdx.x, blk = blockIdx.x;
    int wv = t >> 6;
    if (blk < 64) {                       // W[k][c] -> wt_bf[c][k]
        int gid = blk * 256 + t;
        int c = gid >> 7, k = gid & 127;
        wt_bf[gid] = f2bf(W[k * 128 + c]);
    }
    if (blk >= 64 && blk < 96) {          // zero gsum
        int gid = (blk - 64) * 256 + t;
        gsum[gid] = 0.f;
    }
    for (int i = t; i < 4 * NB; i += 256) cnt[i] = 0;
    __syncthreads();
    int e0 = blk * EPB;
    int* my = cnt + wv * NB;
    for (int e = e0 + t; e < e0 + EPB; e += 256)
        atomicAdd(&my[dst[e] >> 8], 1);
    __syncthreads();
    for (int i = t; i < NB; i += 256)
        table[blk * NB + i] = cnt[i] + cnt[NB + i] + cnt[2 * NB + i] + cnt[3 * NB + i];
}

// ---- KB2a: per-bucket column scan of table (196 blocks) -------------------
__global__ __launch_bounds__(256) void kb2a(int* __restrict__ table,
                                            int* __restrict__ ctot) {
    __shared__ int s[256];
    int t = threadIdx.x, b = blockIdx.x;
    int v = table[t * NB + b];
    s[t] = v;
    __syncthreads();
    for (int off = 1; off < 256; off <<= 1) {
        int a = s[t];
        int w = (t >= off) ? s[t - off] : 0;
        __syncthreads();
        s[t] = a + w;
        __syncthreads();
    }
    table[t * NB + b] = s[t] - v;          // exclusive within column
    if (t == 255) ctot[b] = s[255];
}

// ---- KB2b: exclusive scan of 196 column totals -> bbase -------------------
__global__ __launch_bounds__(256) void kb2b(const int* __restrict__ ctot,
                                            int* __restrict__ bbase) {
    __shared__ int s[256];
    int b = threadIdx.x;
    int v = (b < NB) ? ctot[b] : 0;
    s[b] = v;
    __syncthreads();
    for (int off = 1; off < 256; off <<= 1) {
        int a = s[b];
        int w = (b >= off) ? s[b - off] : 0;
        __syncthreads();
        s[b] = a + w;
        __syncthreads();
    }
    if (b < NB) bbase[b] = s[b] - v;
    if (b == 0) bbase[NB] = EE;
}

// ---- KB3: scatter edges into bucket order (packed dst<<16|src) ------------
__global__ __launch_bounds__(256) void kb3(const int* __restrict__ src,
                                           const int* __restrict__ dst,
                                           const int* __restrict__ table,
                                           const int* __restrict__ bbase,
                                           unsigned* __restrict__ etmp) {
    __shared__ int ofs[NB];
    __shared__ int cur[NB];
    int t = threadIdx.x, blk = blockIdx.x;
    for (int i = t; i < NB; i += 256) {
        ofs[i] = table[blk * NB + i] + bbase[i];
        cur[i] = 0;
    }
    __syncthreads();
    int e0 = blk * EPB;
    for (int e = e0 + t; e < e0 + EPB; e += 256) {
        int d = dst[e];
        int b = d >> 8;
        int r = atomicAdd(&cur[b], 1);
        etmp[ofs[b] + r] = ((unsigned)d << 16) | (unsigned)src[e];
    }
}

// ---- K_CSR: per-bucket  hist -> scan -> row_ptr/dinv -> CSR fill (ushort) -
__global__ __launch_bounds__(256) void k_csr(const unsigned* __restrict__ etmp,
                                             const int* __restrict__ bbase,
                                             int* __restrict__ row_ptr,
                                             float* __restrict__ dinv,
                                             unsigned short* __restrict__ srcs) {
    __shared__ int s[256];
    __shared__ int cur[256];
    int t = threadIdx.x, b = blockIdx.x;
    s[t] = 0;
    __syncthreads();
    int e0 = bbase[b], e1 = bbase[b + 1];
    for (int e = e0 + t; e < e1; e += 256)
        atomicAdd(&s[(etmp[e] >> 16) & 255], 1);
    __syncthreads();
    int v = s[t];
    for (int off = 1; off < 256; off <<= 1) {
        int a = s[t];
        int w = (t >= off) ? s[t - off] : 0;
        __syncthreads();
        s[t] = a + w;
        __syncthreads();
    }
    int excl = s[t] - v + e0;   // e0 == bbase[b] == row_ptr[b*256]
    int node = b * 256 + t;
    if (node < NN) {
        row_ptr[node] = excl;
        dinv[node] = rsqrtf((float)(v + 1));  // +1 self-loop
    }
    if (b == NB - 1 && t == 0) row_ptr[NN] = EE;
    cur[t] = excl;
    __syncthreads();
    for (int e = e0 + t; e < e1; e += 256) {
        unsigned u = etmp[e];
        int slot = atomicAdd(&cur[(u >> 16) & 255], 1);
        srcs[slot] = (unsigned short)(u & 0xffffu);
    }
}

// ---- K4: MFMA GEMM  hs = bf16( (x @ W) * dinv[row] ), direct fp32 x -------
__global__ __launch_bounds__(256) void k_gemm(const float* __restrict__ x,
                                              const unsigned short* __restrict__ wt_bf,
                                              const float* __restrict__ dinv,
                                              unsigned short* __restrict__ hs) {
    int tid = threadIdx.x;
    int w = tid >> 6, lane = tid & 63;
    int m = lane & 15, quad = lane >> 4;
    int r0 = blockIdx.x * 64 + w * 16;        // 782 blocks * 64 = NPAD exactly
    int row = r0 + m;
    frag_cd acc[8];
#pragma unroll
    for (int nt = 0; nt < 8; nt++) acc[nt] = frag_cd{0.f, 0.f, 0.f, 0.f};

#pragma unroll
    for (int k0 = 0; k0 < 128; k0 += 32) {
        unsigned short av[8];
        if (row < NN) {
            const float4* p = (const float4*)(x + (size_t)row * 128 + k0 + quad * 8);
            float4 a0 = p[0], a1 = p[1];
            av[0] = f2bf(a0.x); av[1] = f2bf(a0.y); av[2] = f2bf(a0.z); av[3] = f2bf(a0.w);
            av[4] = f2bf(a1.x); av[5] = f2bf(a1.y); av[6] = f2bf(a1.z); av[7] = f2bf(a1.w);
        } else {
#pragma unroll
            for (int j = 0; j < 8; j++) av[j] = 0;
        }
        frag_ab a = *(const frag_ab*)av;
#pragma unroll
        for (int nt = 0; nt < 8; nt++) {
            frag_ab bfr = *(const frag_ab*)(wt_bf + (size_t)(nt * 16 + m) * 128 + k0 + quad * 8);
            acc[nt] = __builtin_amdgcn_mfma_f32_16x16x32_bf16(a, bfr, acc[nt], 0, 0, 0);
        }
    }
#pragma unroll
    for (int reg = 0; reg < 4; reg++) {
        int gr = r0 + quad * 4 + reg;
        if (gr < NN) {
            float di = dinv[gr];
#pragma unroll
            for (int nt = 0; nt < 8; nt++)
                hs[(size_t)gr * 128 + nt * 16 + m] = f2bf(acc[nt][reg] * di);
        }
    }
}

// ---------------- K5: gather + bias + relu + fused hierarchical pool -------
// 16 quarter-waves/block; qwave = ONE node's 256B row (16 lanes x uint4).
// 16 nodes/block, 3125 blocks (grid exact). 4-deep pipeline, VGPR ~36.
#define ACC8(u) \
    a0 += __uint_as_float((u).x << 16); a1 += __uint_as_float((u).x & 0xffff0000u); \
    a2 += __uint_as_float((u).y << 16); a3 += __uint_as_float((u).y & 0xffff0000u); \
    a4 += __uint_as_float((u).z << 16); a5 += __uint_as_float((u).z & 0xffff0000u); \
    a6 += __uint_as_float((u).w << 16); a7 += __uint_as_float((u).w & 0xffff0000u);

__global__ __launch_bounds__(256) void k_aggr(const uint4* __restrict__ hs4,
                                              const int* __restrict__ row_ptr,
                                              const unsigned short* __restrict__ srcs,
                                              const float* __restrict__ dinv,
                                              const float* __restrict__ bias,
                                              const int* __restrict__ batch,
                                              float* __restrict__ gsum) {
    __shared__ float gacc[8 * 128];   // 4 KB: 8 group slots (span>8 -> global)
    int tid = threadIdx.x;
    int qid = tid >> 4, sub = tid & 15;
    int i_base = blockIdx.x * 16;
    int i = i_base + qid;             // 3125*16 = NN exactly
    int g_first = batch[i_base];
    int gspan = batch[i_base + 15] - g_first + 1;
    bool lds_pool = (gspan <= 8);
    int slots = lds_pool ? gspan : 0;
    for (int idx = tid; idx < slots * 128; idx += 256) gacc[idx] = 0.f;
    __syncthreads();

    const float4* b4 = (const float4*)(bias + sub * 8);
    float4 bb0 = b4[0], bb1 = b4[1];

    float di = dinv[i];
    uint4 su = hs4[(size_t)i * 16 + sub];
    float a0 = __uint_as_float(su.x << 16);
    float a1 = __uint_as_float(su.x & 0xffff0000u);
    float a2 = __uint_as_float(su.y << 16);
    float a3 = __uint_as_float(su.y & 0xffff0000u);
    float a4 = __uint_as_float(su.z << 16);
    float a5 = __uint_as_float(su.z & 0xffff0000u);
    float a6 = __uint_as_float(su.w << 16);
    float a7 = __uint_as_float(su.w & 0xffff0000u);
    int e = row_ptr[i], e1 = row_ptr[i + 1];
    for (; e + 3 < e1; e += 4) {
        int s0 = srcs[e], s1 = srcs[e + 1], s2 = srcs[e + 2], s3 = srcs[e + 3];
        uint4 u0 = hs4[(size_t)s0 * 16 + sub];
        uint4 u1 = hs4[(size_t)s1 * 16 + sub];
        uint4 u2 = hs4[(size_t)s2 * 16 + sub];
        uint4 u3 = hs4[(size_t)s3 * 16 + sub];
        ACC8(u0) ACC8(u1) ACC8(u2) ACC8(u3)
    }
    for (; e < e1; ++e) {
        uint4 u0 = hs4[(size_t)srcs[e] * 16 + sub];
        ACC8(u0)
    }
    float r0 = fmaxf(fmaf(a0, di, bb0.x), 0.f);
    float r1 = fmaxf(fmaf(a1, di, bb0.y), 0.f);
    float r2 = fmaxf(fmaf(a2, di, bb0.z), 0.f);
    float r3 = fmaxf(fmaf(a3, di, bb0.w), 0.f);
    float r4 = fmaxf(fmaf(a4, di, bb1.x), 0.f);
    float r5 = fmaxf(fmaf(a5, di, bb1.y), 0.f);
    float r6 = fmaxf(fmaf(a6, di, bb1.z), 0.f);
    float r7 = fmaxf(fmaf(a7, di, bb1.w), 0.f);
    int lg = batch[i] - g_first;
    float* gp = lds_pool ? &gacc[lg * 128 + sub * 8]
                         : &gsum[(g_first + lg) * 128 + sub * 8];
    atomicAdd(&gp[0], r0); atomicAdd(&gp[1], r1);
    atomicAdd(&gp[2], r2); atomicAdd(&gp[3], r3);
    atomicAdd(&gp[4], r4); atomicAdd(&gp[5], r5);
    atomicAdd(&gp[6], r6); atomicAdd(&gp[7], r7);
    __syncthreads();
    for (int idx = tid; idx < slots * 128; idx += 256) {
        float v = gacc[idx];
        if (v != 0.f)
            atomicAdd(&gsum[(g_first + (idx >> 7)) * 128 + (idx & 127)], v);
    }
}

__device__ inline int lbound(const int* __restrict__ a, int n, int key) {
    int lo = 0, hi = n;
    while (lo < hi) {
        int mid = (lo + hi) >> 1;
        if (a[mid] < key) lo = mid + 1;
        else hi = mid;
    }
    return lo;
}

// ---------------- K7: head (mean, fc1 + relu, actor softmax, critic) -------
__global__ __launch_bounds__(64) void k_head(const float* __restrict__ gsum,
                                             const int* __restrict__ batch,
                                             const float* __restrict__ fc1_w,
                                             const float* __restrict__ fc1_b,
                                             const float* __restrict__ actor_w,
                                             const float* __restrict__ actor_b,
                                             const float* __restrict__ critic_w,
                                             const float* __restrict__ critic_b,
                                             float* __restrict__ out) {
    __shared__ float gs[128];
    __shared__ float zs[64];
    __shared__ float ls[8], es[8];
    int g = blockIdx.x, t = threadIdx.x;
    int lo = lbound(batch, NN, g), hi = lbound(batch, NN, g + 1);
    float invc = 1.f / fmaxf((float)(hi - lo), 1.f);
    gs[t] = gsum[g * 128 + t] * invc;
    gs[t + 64] = gsum[g * 128 + 64 + t] * invc;
    __syncthreads();
    float z = fc1_b[t];
    for (int k = 0; k < 128; k++) z = fmaf(gs[k], fc1_w[k * 64 + t], z);
    zs[t] = fmaxf(z, 0.f);
    __syncthreads();
    if (t < 8) {
        float l = actor_b[t];
        for (int k = 0; k < 64; k++) l = fmaf(zs[k], actor_w[k * 8 + t], l);
        ls[t] = l;
    }
    __syncthreads();
    if (t < 8) {
        float m = ls[0];
#pragma unroll
        for (int j = 1; j < 8; j++) m = fmaxf(m, ls[j]);
        es[t] = expf(ls[t] - m);
    }
    __syncthreads();
    if (t < 8) {
        float ssum = 0.f;
#pragma unroll
        for (int j = 0; j < 8; j++) ssum += es[j];
        out[g * 8 + t] = es[t] / ssum;
    }
    if (t == 32) {
        float v = critic_b[0];
        for (int k = 0; k < 64; k++) v = fmaf(zs[k], critic_w[k], v);
        out[GG * TT + g] = v;
    }
}

extern "C" void kernel_launch(void* const* d_in, const int* in_sizes, int n_in,
                              void* d_out, int out_size, void* d_ws, size_t ws_size,
                              hipStream_t stream) {
    const float* x        = (const float*)d_in[0];
    const int*   ei       = (const int*)d_in[1];
    const int*   batch    = (const int*)d_in[2];
    const float* W        = (const float*)d_in[3];
    const float* b        = (const float*)d_in[4];
    const float* fc1_w    = (const float*)d_in[5];
    const float* fc1_b    = (const float*)d_in[6];
    const float* actor_w  = (const float*)d_in[7];
    const float* actor_b  = (const float*)d_in[8];
    const float* critic_w = (const float*)d_in[9];
    const float* critic_b = (const float*)d_in[10];
    float* out = (float*)d_out;

    char* ws = (char*)d_ws;
    size_t off = 0;
    unsigned short* hs    = (unsigned short*)(ws + off); off += (size_t)NN * 128 * 2 + 64;  // 12.8 MB
    unsigned short* wt_bf = (unsigned short*)(ws + off); off += (size_t)128 * 128 * 2;      // 32 KB
    float* dinv      = (float*)(ws + off);    off += (size_t)NN * 4;
    int*   row_ptr   = (int*)(ws + off);      off += (size_t)(NN + 1) * 4 + 12;
    unsigned short* srcs = (unsigned short*)(ws + off); off += (size_t)EE * 2 + 32;  // 1.6 MB
    unsigned* etmp   = (unsigned*)(ws + off); off += (size_t)EE * 4;       // 3.2 MB
    int*   table     = (int*)(ws + off);      off += (size_t)NSB * NB * 4; // 200 KB
    int*   bbase     = (int*)(ws + off);      off += (size_t)(NB + 1) * 4 + 12;
    int*   ctot      = (int*)(ws + off);      off += (size_t)NB * 4 + 16;
    float* gsum      = (float*)(ws + off);    off += (size_t)GG * HH * 4;

    const int* src = ei;        // edge_index[0]
    const int* dst = ei + EE;   // edge_index[1]

    k_front<<<NSB, 256, 0, stream>>>(dst, W, table, wt_bf, gsum);
    kb2a<<<NB, 256, 0, stream>>>(table, ctot);
    kb2b<<<1, 256, 0, stream>>>(ctot, bbase);
    kb3<<<NSB, 256, 0, stream>>>(src, dst, table, bbase, etmp);
    k_csr<<<NB, 256, 0, stream>>>(etmp, bbase, row_ptr, dinv, srcs);
    k_gemm<<<NPAD / 64, 256, 0, stream>>>(x, wt_bf, dinv, hs);
    k_aggr<<<NN / 16, 256, 0, stream>>>((const uint4*)hs, row_ptr, srcs,
                                        dinv, b, batch, gsum);
    k_head<<<GG, 64, 0, stream>>>(gsum, batch, fc1_w, fc1_b, actor_w, actor_b,
                                  critic_w, critic_b, out);
}

// Round 14
// 201.093 us; speedup vs baseline: 1.4128x; 1.0034x over previous
//
#include <hip/hip_runtime.h>
#include <hip/hip_bf16.h>

#define NN 50000
#define EE 800000
#define FF 128
#define HH 128
#define HID2 64
#define TT 8
#define GG 64
#define NB 196          // buckets of 256 dst nodes (NN < 196*256; NN < 2^16)
#define NSB 256         // scatter blocks
#define EPB (EE / NSB)  // 3125 edges per scatter block
#define NPAD 50048      // NN padded to 64 (782 * 64)
#define SLAB4 ((size_t)NN * 4)    // uint4s per feature-quarter slab (3.2 MB)
#define ANB 391         // aggr node-blocks per quarter (391*128 = 50048)

using frag_ab = __attribute__((ext_vector_type(8))) short;  // 8 bf16
using frag_cd = __attribute__((ext_vector_type(4))) float;  // 4 fp32

__device__ inline unsigned short f2bf(float f) {
    union { float f; unsigned u; } v; v.f = f;
    unsigned r = v.u + 0x7fff + ((v.u >> 16) & 1);  // RNE
    return (unsigned short)(r >> 16);
}

// ---- K_FRONT: hist (4 per-wave sub-hists) + W->Wt bf16 + gsum zero --------
__global__ __launch_bounds__(256) void k_front(const int* __restrict__ dst,
                                               const float* __restrict__ W,
                                               int* __restrict__ table,
                                               unsigned short* __restrict__ wt_bf,
                                               float* __restrict__ gsum) {
    __shared__ int cnt[4 * NB];
    int t = threadIdx.x, blk = blockIdx.x;
    int wv = t >> 6;
    if (blk < 64) {                       // W[k][c] -> wt_bf[c][k]
        int gid = blk * 256 + t;
        int c = gid >> 7, k = gid & 127;
        wt_bf[gid] = f2bf(W[k * 128 + c]);
    }
    if (blk >= 64 && blk < 96) {          // zero gsum
        int gid = (blk - 64) * 256 + t;
        gsum[gid] = 0.f;
    }
    for (int i = t; i < 4 * NB; i += 256) cnt[i] = 0;
    __syncthreads();
    int e0 = blk * EPB;
    int* my = cnt + wv * NB;
    for (int e = e0 + t; e < e0 + EPB; e += 256)
        atomicAdd(&my[dst[e] >> 8], 1);
    __syncthreads();
    for (int i = t; i < NB; i += 256)
        table[blk * NB + i] = cnt[i] + cnt[NB + i] + cnt[2 * NB + i] + cnt[3 * NB + i];
}

// ---- KB2a: per-bucket column scan of table (196 blocks) -------------------
__global__ __launch_bounds__(256) void kb2a(int* __restrict__ table,
                                            int* __restrict__ ctot) {
    __shared__ int s[256];
    int t = threadIdx.x, b = blockIdx.x;
    int v = table[t * NB + b];
    s[t] = v;
    __syncthreads();
    for (int off = 1; off < 256; off <<= 1) {
        int a = s[t];
        int w = (t >= off) ? s[t - off] : 0;
        __syncthreads();
        s[t] = a + w;
        __syncthreads();
    }
    table[t * NB + b] = s[t] - v;          // exclusive within column
    if (t == 255) ctot[b] = s[255];
}

// ---- KB2b: exclusive scan of 196 column totals -> bbase -------------------
__global__ __launch_bounds__(256) void kb2b(const int* __restrict__ ctot,
                                            int* __restrict__ bbase) {
    __shared__ int s[256];
    int b = threadIdx.x;
    int v = (b < NB) ? ctot[b] : 0;
    s[b] = v;
    __syncthreads();
    for (int off = 1; off < 256; off <<= 1) {
        int a = s[b];
        int w = (b >= off) ? s[b - off] : 0;
        __syncthreads();
        s[b] = a + w;
        __syncthreads();
    }
    if (b < NB) bbase[b] = s[b] - v;
    if (b == 0) bbase[NB] = EE;
}

// ---- KB3: scatter edges into bucket order (packed dst<<16|src) ------------
__global__ __launch_bounds__(256) void kb3(const int* __restrict__ src,
                                           const int* __restrict__ dst,
                                           const int* __restrict__ table,
                                           const int* __restrict__ bbase,
                                           unsigned* __restrict__ etmp) {
    __shared__ int ofs[NB];
    __shared__ int cur[NB];
    int t = threadIdx.x, blk = blockIdx.x;
    for (int i = t; i < NB; i += 256) {
        ofs[i] = table[blk * NB + i] + bbase[i];
        cur[i] = 0;
    }
    __syncthreads();
    int e0 = blk * EPB;
    for (int e = e0 + t; e < e0 + EPB; e += 256) {
        int d = dst[e];
        int b = d >> 8;
        int r = atomicAdd(&cur[b], 1);
        etmp[ofs[b] + r] = ((unsigned)d << 16) | (unsigned)src[e];
    }
}

// ---- K_CSR: per-bucket  hist -> scan -> row_ptr/dinv -> CSR fill (ushort) -
__global__ __launch_bounds__(256) void k_csr(const unsigned* __restrict__ etmp,
                                             const int* __restrict__ bbase,
                                             int* __restrict__ row_ptr,
                                             float* __restrict__ dinv,
                                             unsigned short* __restrict__ srcs) {
    __shared__ int s[256];
    __shared__ int cur[256];
    int t = threadIdx.x, b = blockIdx.x;
    s[t] = 0;
    __syncthreads();
    int e0 = bbase[b], e1 = bbase[b + 1];
    for (int e = e0 + t; e < e1; e += 256)
        atomicAdd(&s[(etmp[e] >> 16) & 255], 1);
    __syncthreads();
    int v = s[t];
    for (int off = 1; off < 256; off <<= 1) {
        int a = s[t];
        int w = (t >= off) ? s[t - off] : 0;
        __syncthreads();
        s[t] = a + w;
        __syncthreads();
    }
    int excl = s[t] - v + e0;   // e0 == bbase[b] == row_ptr[b*256]
    int node = b * 256 + t;
    if (node < NN) {
        row_ptr[node] = excl;
        dinv[node] = rsqrtf((float)(v + 1));  // +1 self-loop
    }
    if (b == NB - 1 && t == 0) row_ptr[NN] = EE;
    cur[t] = excl;
    __syncthreads();
    for (int e = e0 + t; e < e1; e += 256) {
        unsigned u = etmp[e];
        int slot = atomicAdd(&cur[(u >> 16) & 255], 1);
        srcs[slot] = (unsigned short)(u & 0xffffu);
    }
}

// ---- K4: MFMA GEMM  hsq = bf16( (x @ W) * dinv[row] ), slab layout --------
// Slab q holds feature cols [q*32, q*32+32): hsq[q*SLAB + row*32 + (c&31)].
__global__ __launch_bounds__(256) void k_gemm(const float* __restrict__ x,
                                              const unsigned short* __restrict__ wt_bf,
                                              const float* __restrict__ dinv,
                                              unsigned short* __restrict__ hsq) {
    int tid = threadIdx.x;
    int w = tid >> 6, lane = tid & 63;
    int m = lane & 15, quad = lane >> 4;
    int r0 = blockIdx.x * 64 + w * 16;        // 782 blocks * 64 = NPAD exactly
    int row = r0 + m;
    frag_cd acc[8];
#pragma unroll
    for (int nt = 0; nt < 8; nt++) acc[nt] = frag_cd{0.f, 0.f, 0.f, 0.f};

#pragma unroll
    for (int k0 = 0; k0 < 128; k0 += 32) {
        unsigned short av[8];
        if (row < NN) {
            const float4* p = (const float4*)(x + (size_t)row * 128 + k0 + quad * 8);
            float4 a0 = p[0], a1 = p[1];
            av[0] = f2bf(a0.x); av[1] = f2bf(a0.y); av[2] = f2bf(a0.z); av[3] = f2bf(a0.w);
            av[4] = f2bf(a1.x); av[5] = f2bf(a1.y); av[6] = f2bf(a1.z); av[7] = f2bf(a1.w);
        } else {
#pragma unroll
            for (int j = 0; j < 8; j++) av[j] = 0;
        }
        frag_ab a = *(const frag_ab*)av;
#pragma unroll
        for (int nt = 0; nt < 8; nt++) {
            frag_ab bfr = *(const frag_ab*)(wt_bf + (size_t)(nt * 16 + m) * 128 + k0 + quad * 8);
            acc[nt] = __builtin_amdgcn_mfma_f32_16x16x32_bf16(a, bfr, acc[nt], 0, 0, 0);
        }
    }
#pragma unroll
    for (int reg = 0; reg < 4; reg++) {
        int gr = r0 + quad * 4 + reg;
        if (gr < NN) {
            float di = dinv[gr];
#pragma unroll
            for (int nt = 0; nt < 8; nt++) {
                int c = nt * 16 + m;
                hsq[(size_t)(c >> 5) * (SLAB4 * 8) + (size_t)gr * 32 + (c & 31)] =
                    f2bf(acc[nt][reg] * di);
            }
        }
    }
}

// ---- K5: XCD-partitioned slab gather + bias + relu + fused pool -----------
// q = blockIdx & 3: with round-robin block->XCD (%8) dispatch, each XCD
// reads ONE 3.2 MB slab -> L2-resident. 4 lanes per node (64 B quarter-row),
// 2 nodes sequential per lane-group, 128 nodes/block, 391*4 blocks.
#define ACC8(u) \
    a0 += __uint_as_float((u).x << 16); a1 += __uint_as_float((u).x & 0xffff0000u); \
    a2 += __uint_as_float((u).y << 16); a3 += __uint_as_float((u).y & 0xffff0000u); \
    a4 += __uint_as_float((u).z << 16); a5 += __uint_as_float((u).z & 0xffff0000u); \
    a6 += __uint_as_float((u).w << 16); a7 += __uint_as_float((u).w & 0xffff0000u);

__global__ __launch_bounds__(256) void k_aggr(const uint4* __restrict__ hsq4,
                                              const int* __restrict__ row_ptr,
                                              const unsigned short* __restrict__ srcs,
                                              const float* __restrict__ dinv,
                                              const float* __restrict__ bias,
                                              const int* __restrict__ batch,
                                              float* __restrict__ gsum) {
    __shared__ float gacc[8 * 32];   // 1 KB: 8 group slots x 32 feats
    int t = threadIdx.x;
    int q = blockIdx.x & 3;          // feature quarter == XCD partition
    int nb = blockIdx.x >> 2;
    int grp = t >> 2, j = t & 3;
    int i_base = nb * 128;
    int last = i_base + 127; if (last >= NN) last = NN - 1;
    int g_first = batch[i_base];
    int gspan = batch[last] - g_first + 1;
    bool lds_pool = (gspan <= 8);
    int slots = lds_pool ? gspan : 0;
    if (t < slots * 32) gacc[t] = 0.f;
    __syncthreads();

    const uint4* slab4 = hsq4 + (size_t)q * SLAB4;
    const float4* b4 = (const float4*)(bias + q * 32 + j * 8);
    float4 bb0 = b4[0], bb1 = b4[1];

    for (int n = 0; n < 2; n++) {
        int i = i_base + grp * 2 + n;
        if (i >= NN) break;
        float di = dinv[i];
        uint4 su = slab4[(size_t)i * 4 + j];
        float a0 = __uint_as_float(su.x << 16);
        float a1 = __uint_as_float(su.x & 0xffff0000u);
        float a2 = __uint_as_float(su.y << 16);
        float a3 = __uint_as_float(su.y & 0xffff0000u);
        float a4 = __uint_as_float(su.z << 16);
        float a5 = __uint_as_float(su.z & 0xffff0000u);
        float a6 = __uint_as_float(su.w << 16);
        float a7 = __uint_as_float(su.w & 0xffff0000u);
        int e = row_ptr[i], e1 = row_ptr[i + 1];
        for (; e + 3 < e1; e += 4) {
            int s0 = srcs[e], s1 = srcs[e + 1], s2 = srcs[e + 2], s3 = srcs[e + 3];
            uint4 u0 = slab4[(size_t)s0 * 4 + j];
            uint4 u1 = slab4[(size_t)s1 * 4 + j];
            uint4 u2 = slab4[(size_t)s2 * 4 + j];
            uint4 u3 = slab4[(size_t)s3 * 4 + j];
            ACC8(u0) ACC8(u1) ACC8(u2) ACC8(u3)
        }
        for (; e < e1; ++e) {
            uint4 u0 = slab4[(size_t)srcs[e] * 4 + j];
            ACC8(u0)
        }
        float r0 = fmaxf(fmaf(a0, di, bb0.x), 0.f);
        float r1 = fmaxf(fmaf(a1, di, bb0.y), 0.f);
        float r2 = fmaxf(fmaf(a2, di, bb0.z), 0.f);
        float r3 = fmaxf(fmaf(a3, di, bb0.w), 0.f);
        float r4 = fmaxf(fmaf(a4, di, bb1.x), 0.f);
        float r5 = fmaxf(fmaf(a5, di, bb1.y), 0.f);
        float r6 = fmaxf(fmaf(a6, di, bb1.z), 0.f);
        float r7 = fmaxf(fmaf(a7, di, bb1.w), 0.f);
        int lg = batch[i] - g_first;
        float* gp = lds_pool ? &gacc[lg * 32 + j * 8]
                             : &gsum[(g_first + lg) * 128 + q * 32 + j * 8];
        atomicAdd(&gp[0], r0); atomicAdd(&gp[1], r1);
        atomicAdd(&gp[2], r2); atomicAdd(&gp[3], r3);
        atomicAdd(&gp[4], r4); atomicAdd(&gp[5], r5);
        atomicAdd(&gp[6], r6); atomicAdd(&gp[7], r7);
    }
    __syncthreads();
    if (t < slots * 32) {
        float v = gacc[t];
        if (v != 0.f)
            atomicAdd(&gsum[(g_first + (t >> 5)) * 128 + q * 32 + (t & 31)], v);
    }
}

__device__ inline int lbound(const int* __restrict__ a, int n, int key) {
    int lo = 0, hi = n;
    while (lo < hi) {
        int mid = (lo + hi) >> 1;
        if (a[mid] < key) lo = mid + 1;
        else hi = mid;
    }
    return lo;
}

// ---------------- K7: head (mean, fc1 + relu, actor softmax, critic) -------
__global__ __launch_bounds__(64) void k_head(const float* __restrict__ gsum,
                                             const int* __restrict__ batch,
                                             const float* __restrict__ fc1_w,
                                             const float* __restrict__ fc1_b,
                                             const float* __restrict__ actor_w,
                                             const float* __restrict__ actor_b,
                                             const float* __restrict__ critic_w,
                                             const float* __restrict__ critic_b,
                                             float* __restrict__ out) {
    __shared__ float gs[128];
    __shared__ float zs[64];
    __shared__ float ls[8], es[8];
    int g = blockIdx.x, t = threadIdx.x;
    int lo = lbound(batch, NN, g), hi = lbound(batch, NN, g + 1);
    float invc = 1.f / fmaxf((float)(hi - lo), 1.f);
    gs[t] = gsum[g * 128 + t] * invc;
    gs[t + 64] = gsum[g * 128 + 64 + t] * invc;
    __syncthreads();
    float z = fc1_b[t];
    for (int k = 0; k < 128; k++) z = fmaf(gs[k], fc1_w[k * 64 + t], z);
    zs[t] = fmaxf(z, 0.f);
    __syncthreads();
    if (t < 8) {
        float l = actor_b[t];
        for (int k = 0; k < 64; k++) l = fmaf(zs[k], actor_w[k * 8 + t], l);
        ls[t] = l;
    }
    __syncthreads();
    if (t < 8) {
        float m = ls[0];
#pragma unroll
        for (int j = 1; j < 8; j++) m = fmaxf(m, ls[j]);
        es[t] = expf(ls[t] - m);
    }
    __syncthreads();
    if (t < 8) {
        float ssum = 0.f;
#pragma unroll
        for (int j = 0; j < 8; j++) ssum += es[j];
        out[g * 8 + t] = es[t] / ssum;
    }
    if (t == 32) {
        float v = critic_b[0];
        for (int k = 0; k < 64; k++) v = fmaf(zs[k], critic_w[k], v);
        out[GG * TT + g] = v;
    }
}

extern "C" void kernel_launch(void* const* d_in, const int* in_sizes, int n_in,
                              void* d_out, int out_size, void* d_ws, size_t ws_size,
                              hipStream_t stream) {
    const float* x        = (const float*)d_in[0];
    const int*   ei       = (const int*)d_in[1];
    const int*   batch    = (const int*)d_in[2];
    const float* W        = (const float*)d_in[3];
    const float* b        = (const float*)d_in[4];
    const float* fc1_w    = (const float*)d_in[5];
    const float* fc1_b    = (const float*)d_in[6];
    const float* actor_w  = (const float*)d_in[7];
    const float* actor_b  = (const float*)d_in[8];
    const float* critic_w = (const float*)d_in[9];
    const float* critic_b = (const float*)d_in[10];
    float* out = (float*)d_out;

    char* ws = (char*)d_ws;
    size_t off = 0;
    unsigned short* hsq   = (unsigned short*)(ws + off); off += (size_t)NN * 128 * 2 + 64;  // 12.8 MB
    unsigned short* wt_bf = (unsigned short*)(ws + off); off += (size_t)128 * 128 * 2;      // 32 KB
    float* dinv      = (float*)(ws + off);    off += (size_t)NN * 4;
    int*   row_ptr   = (int*)(ws + off);      off += (size_t)(NN + 1) * 4 + 12;
    unsigned short* srcs = (unsigned short*)(ws + off); off += (size_t)EE * 2 + 32;  // 1.6 MB
    unsigned* etmp   = (unsigned*)(ws + off); off += (size_t)EE * 4;       // 3.2 MB
    int*   table     = (int*)(ws + off);      off += (size_t)NSB * NB * 4; // 200 KB
    int*   bbase     = (int*)(ws + off);      off += (size_t)(NB + 1) * 4 + 12;
    int*   ctot      = (int*)(ws + off);      off += (size_t)NB * 4 + 16;
    float* gsum      = (float*)(ws + off);    off += (size_t)GG * HH * 4;

    const int* src = ei;        // edge_index[0]
    const int* dst = ei + EE;   // edge_index[1]

    k_front<<<NSB, 256, 0, stream>>>(dst, W, table, wt_bf, gsum);
    kb2a<<<NB, 256, 0, stream>>>(table, ctot);
    kb2b<<<1, 256, 0, stream>>>(ctot, bbase);
    kb3<<<NSB, 256, 0, stream>>>(src, dst, table, bbase, etmp);
    k_csr<<<NB, 256, 0, stream>>>(etmp, bbase, row_ptr, dinv, srcs);
    k_gemm<<<NPAD / 64, 256, 0, stream>>>(x, wt_bf, dinv, hsq);
    k_aggr<<<ANB * 4, 256, 0, stream>>>((const uint4*)hsq, row_ptr, srcs,
                                        dinv, b, batch, gsum);
    k_head<<<GG, 64, 0, stream>>>(gsum, batch, fc1_w, fc1_b, actor_w, actor_b,
                                  critic_w, critic_b, out);
}